// Round 6
// baseline (132.287 us; speedup 1.0000x reference)
//
#include <hip/hip_runtime.h>

#define BB 2
#define LL 4096
#define SS 4096
#define HH 8
#define DD 64
#define UU 45
#define SCALE 0.125f

// ---------------------------------------------------------------------------
// K1 (split-u): partial M over u-range [0,23) or [23,45) per block.
// Structure as round-5 (16-lane slots, per-head float4 gather, width-16
// shuffle reduce, bh in low 4 bits -> XCD pin; per-XCD K working set 2MB,
// L2-resident). Splitting u across 2x blocks doubles wave count -> 2x
// outstanding L2 requests to close the 45%-of-L2-peak latency gap.
// Partials (mx, sm) -> ws; combined inside k_topk.
// ---------------------------------------------------------------------------
__global__ __launch_bounds__(256) void k_compute_M_part(
    const float* __restrict__ q, const float* __restrict__ k,
    const int* __restrict__ idx, float2* __restrict__ part) {
  __shared__ int sidx[16 * UU];
  int tid = threadIdx.x;
  int bh = blockIdx.x & 15;            // low bits -> XCD pin
  int uh = (blockIdx.x >> 4) & 1;      // u-half
  int l0 = (blockIdx.x >> 5) << 4;     // 16 l per block
  for (int i = tid; i < 16 * UU; i += 256) sidx[i] = idx[(long)l0 * UU + i];
  __syncthreads();

  int slot = tid >> 4;    // which l within block
  int sub  = tid & 15;    // d-quarter
  int l = l0 + slot;
  int b = bh >> 3, h = bh & 7;

  const float4* qp = (const float4*)(q + (((long)b * LL + l) * HH + h) * DD);
  float4 qq = qp[sub];
  const float* kb = k + (long)b * SS * HH * DD + h * DD;

  int u0 = uh ? 23 : 0;
  int u1 = uh ? UU : 23;
  float mx = -INFINITY, sm = 0.f;
  #pragma unroll 8
  for (int u = u0; u < u1; ++u) {
    int s = sidx[slot * UU + u];
    float4 kk4 = ((const float4*)(kb + (long)s * (HH * DD)))[sub];
    float p = qq.x * kk4.x + qq.y * kk4.y + qq.z * kk4.z + qq.w * kk4.w;
    #pragma unroll
    for (int off = 8; off; off >>= 1) p += __shfl_xor(p, off, 16);
    mx = fmaxf(mx, p);
    sm += p;
  }
  if (sub == 0) part[(((uh << 4) | bh) << 12) | l] = make_float2(mx, sm);
}

// Fallback mono K1 (round-5 version; M -> attn-region overlay).
__global__ __launch_bounds__(256) void k_compute_M(
    const float* __restrict__ q, const float* __restrict__ k,
    const int* __restrict__ idx, float* __restrict__ M) {
  __shared__ int sidx[16 * UU];
  int tid = threadIdx.x;
  int bh = blockIdx.x & 15;
  int l0 = (blockIdx.x >> 4) << 4;
  for (int i = tid; i < 16 * UU; i += 256) sidx[i] = idx[(long)l0 * UU + i];
  __syncthreads();
  int slot = tid >> 4, sub = tid & 15;
  int l = l0 + slot;
  int b = bh >> 3, h = bh & 7;
  const float4* qp = (const float4*)(q + (((long)b * LL + l) * HH + h) * DD);
  float4 qq = qp[sub];
  const float* kb = k + (long)b * SS * HH * DD + h * DD;
  float mx = -INFINITY, sm = 0.f;
  #pragma unroll 5
  for (int u = 0; u < UU; ++u) {
    int s = sidx[slot * UU + u];
    float4 kk4 = ((const float4*)(kb + (long)s * (HH * DD)))[sub];
    float p = qq.x * kk4.x + qq.y * kk4.y + qq.z * kk4.z + qq.w * kk4.w;
    #pragma unroll
    for (int off = 8; off; off >>= 1) p += __shfl_xor(p, off, 16);
    mx = fmaxf(mx, p);
    sm += p;
  }
  if (sub == 0) M[(long)bh * LL + l] = mx - sm * (1.0f / SS);
}

// ---------------------------------------------------------------------------
// K2: top-45 per (b,h) via 4-pass radix-select; combines the two u-half
// partials into M inline while building orderable keys. jax.lax.top_k
// semantics: value desc, ties -> lowest index. One block per bh.
// ---------------------------------------------------------------------------
template <bool FROM_PART>
__global__ __launch_bounds__(256) void k_topk_t(
    const float2* __restrict__ part, const float* __restrict__ M,
    int* __restrict__ Mtop) {
  __shared__ unsigned keys[LL];        // 16 KB orderable keys
  __shared__ int hist[256];
  __shared__ int wsum[4];
  __shared__ int sh_bin, sh_gtwin;
  __shared__ int ccount, ecount;
  __shared__ unsigned cand_key[64];
  __shared__ int cand_idx[64];
  __shared__ int elist[LL];            // ==T indices (worst-case capacity)

  int bh = blockIdx.x, tid = threadIdx.x;
  int lane = tid & 63, w = tid >> 6;
  if (FROM_PART) {
    const float2* pa = part + ((long)bh << 12);
    const float2* pb = part + ((long)(16 + bh) << 12);
    for (int i = tid; i < LL; i += 256) {
      float2 A = pa[i], Bv = pb[i];
      float Mv = fmaxf(A.x, Bv.x) - (A.y + Bv.y) * (1.0f / SS);
      union { float f; unsigned u; } cv; cv.f = Mv;
      keys[i] = (cv.u & 0x80000000u) ? ~cv.u : (cv.u | 0x80000000u);
    }
  } else {
    const float* m = M + (long)bh * LL;
    for (int i = tid; i < LL; i += 256) {
      union { float f; unsigned u; } cv; cv.f = m[i];
      keys[i] = (cv.u & 0x80000000u) ? ~cv.u : (cv.u | 0x80000000u);
    }
  }
  if (tid == 0) { ccount = 0; ecount = 0; }
  __syncthreads();

  unsigned prefix = 0, pmask = 0;
  int need = UU, above = 0;

  for (int shift = 24; shift >= 0; shift -= 8) {
    hist[tid] = 0;
    __syncthreads();
    #pragma unroll
    for (int j = 0; j < 16; ++j) {
      unsigned kk = keys[tid + (j << 8)];
      if ((kk & pmask) == prefix) atomicAdd(&hist[(kk >> shift) & 255], 1);
    }
    __syncthreads();
    int v = hist[tid];
    int sfx = v;
    #pragma unroll
    for (int st = 1; st < 64; st <<= 1) {
      int o = __shfl_down(sfx, st, 64);
      if (lane + st < 64) sfx += o;
    }
    if (lane == 0) wsum[w] = sfx;
    __syncthreads();
    for (int t = w + 1; t < 4; ++t) sfx += wsum[t];
    int gt = sfx - v;
    if (gt < need && sfx >= need) {
      sh_bin = tid;
      sh_gtwin = gt;
    }
    __syncthreads();
    prefix |= ((unsigned)sh_bin << shift);
    pmask  |= (255u << shift);
    need  -= sh_gtwin;
    above += sh_gtwin;
    __syncthreads();
  }
  unsigned T = prefix;

  #pragma unroll
  for (int j = 0; j < 16; ++j) {
    int i = tid + (j << 8);
    unsigned kk = keys[i];
    if (kk > T)      { int p = atomicAdd(&ccount, 1); cand_key[p] = kk; cand_idx[p] = i; }
    else if (kk == T){ int p = atomicAdd(&ecount, 1); elist[p] = i; }
  }
  __syncthreads();
  int nc = ccount, ne = ecount;
  for (int t = tid; t < nc; t += 256) {
    unsigned kk = cand_key[t]; int ii = cand_idx[t]; int r = 0;
    for (int j = 0; j < nc; ++j)
      r += (cand_key[j] > kk) || (cand_key[j] == kk && cand_idx[j] < ii);
    Mtop[bh * UU + r] = ii;
  }
  for (int t = tid; t < ne; t += 256) {
    int ii = elist[t]; int r = 0;
    for (int j = 0; j < ne; ++j) r += (elist[j] < ii);
    if (r < need) Mtop[bh * UU + above + r] = ii;
  }
}

// ---------------------------------------------------------------------------
// K3: scores[u][s] = (Qr[u] . K[s]) * SCALE for one bh, 256 s per block.
// ---------------------------------------------------------------------------
__global__ __launch_bounds__(256) void k_scores(
    const float* __restrict__ q, const float* __restrict__ k,
    const int* __restrict__ Mtop, float* __restrict__ attn) {
  __shared__ float qr[UU * DD];
  int bh = blockIdx.y;
  int b = bh >> 3, h = bh & 7;
  for (int i = threadIdx.x; i < UU * DD; i += 256) {
    int u = i >> 6, d = i & 63;
    int l = Mtop[bh * UU + u];
    qr[i] = q[(((long)b * LL + l) * HH + h) * DD + d];
  }
  __syncthreads();
  int s = blockIdx.x * 256 + threadIdx.x;
  float4 kr[16];
  const float4* kp = (const float4*)(k + (((long)b * SS + s) * HH + h) * DD);
  #pragma unroll
  for (int j = 0; j < 16; ++j) kr[j] = kp[j];
  for (int u = 0; u < UU; ++u) {
    const float4* qp = (const float4*)(qr + u * DD);
    float acc = 0.f;
    #pragma unroll
    for (int j = 0; j < 16; ++j) {
      float4 qq = qp[j];
      acc += qq.x * kr[j].x + qq.y * kr[j].y + qq.z * kr[j].z + qq.w * kr[j].w;
    }
    attn[((long)bh * UU + u) * SS + s] = acc * SCALE;
  }
}

// ---------------------------------------------------------------------------
// K4: row softmax over S=4096, one block per row (720 rows), in place.
// ---------------------------------------------------------------------------
__global__ __launch_bounds__(256) void k_softmax(float* __restrict__ attn) {
  __shared__ float red[256];
  long row = blockIdx.x;
  float* a = attn + row * SS;
  float v[16];
  float mx = -INFINITY;
  #pragma unroll
  for (int j = 0; j < 16; ++j) {
    v[j] = a[j * 256 + threadIdx.x];
    mx = fmaxf(mx, v[j]);
  }
  red[threadIdx.x] = mx;
  __syncthreads();
  for (int st = 128; st; st >>= 1) {
    if (threadIdx.x < st) red[threadIdx.x] = fmaxf(red[threadIdx.x], red[threadIdx.x + st]);
    __syncthreads();
  }
  mx = red[0];
  __syncthreads();
  float sm = 0.f;
  #pragma unroll
  for (int j = 0; j < 16; ++j) {
    v[j] = __expf(v[j] - mx);
    sm += v[j];
  }
  red[threadIdx.x] = sm;
  __syncthreads();
  for (int st = 128; st; st >>= 1) {
    if (threadIdx.x < st) red[threadIdx.x] += red[threadIdx.x + st];
    __syncthreads();
  }
  float inv = 1.0f / red[0];
  #pragma unroll
  for (int j = 0; j < 16; ++j) a[j * 256 + threadIdx.x] = v[j] * inv;
}

// ---------------------------------------------------------------------------
// K5a: chunked context partials. grid = (nch, B*H); block = 256 (4 waves).
// All 45 u-accumulators in registers (lane = d); attn chunk staged transposed
// in LDS (row stride 52). V and attn each read once from HBM. Partials -> ws.
// ---------------------------------------------------------------------------
__global__ __launch_bounds__(256) void k_context_part(
    const float* __restrict__ attn, const float* __restrict__ v,
    float* __restrict__ part, int nch) {
  __shared__ float smem[4 * UU * DD];   // 11520 floats; staging uses 128*52
  int ch = blockIdx.x, bh = blockIdx.y;
  int b = bh >> 3, h = bh & 7;
  int tid = threadIdx.x;
  int ln = tid & 63, w = tid >> 6;
  int chunk = SS / nch;
  int s0 = ch * chunk;
  int nsub = chunk >> 7;                // 128-s sub-tiles

  float acc[UU];
  #pragma unroll
  for (int u = 0; u < UU; ++u) acc[u] = 0.f;

  const float* vb = v + (long)b * SS * HH * DD + h * DD + ln;

  for (int sub = 0; sub < nsub; ++sub) {
    int sb = s0 + (sub << 7);
    __syncthreads();
    for (int i = tid; i < UU * 128; i += 256) {
      int u = i >> 7, si = i & 127;
      smem[si * 52 + u] = attn[((long)bh * UU + u) * SS + sb + si];
    }
    __syncthreads();
    #pragma unroll 2
    for (int j = 0; j < 32; ++j) {
      int sl = (j << 2) + w;
      float vd = vb[(long)(sb + sl) * (HH * DD)];
      const float* ar = smem + sl * 52;
      #pragma unroll
      for (int g = 0; g < 11; ++g) {
        float4 aa = *(const float4*)(ar + g * 4);
        acc[g * 4 + 0] += aa.x * vd;
        acc[g * 4 + 1] += aa.y * vd;
        acc[g * 4 + 2] += aa.z * vd;
        acc[g * 4 + 3] += aa.w * vd;
      }
      acc[44] += ar[44] * vd;
    }
  }

  __syncthreads();
  #pragma unroll
  for (int u = 0; u < UU; ++u) smem[(w * UU + u) * DD + ln] = acc[u];
  __syncthreads();
  long base = ((long)bh * nch + ch) * (UU * DD);
  for (int i = tid; i < UU * DD; i += 256)
    part[base + i] = smem[i] + smem[UU * DD + i] + smem[2 * UU * DD + i] + smem[3 * UU * DD + i];
}

// K5b: sum partials over chunks. 46080 outputs.
__global__ __launch_bounds__(256) void k_context_reduce(
    const float* __restrict__ part, float* __restrict__ ctx, int nch) {
  int g = blockIdx.x * 256 + threadIdx.x;     // < B*H*U*D = 46080
  int bh = g / (UU * DD);
  int r  = g - bh * (UU * DD);
  float s = 0.f;
  for (int ch = 0; ch < nch; ++ch)
    s += part[((long)bh * nch + ch) * (UU * DD) + r];
  ctx[g] = s;
}

// Fallback (row-per-block context) if d_ws is too small.
__global__ __launch_bounds__(256) void k_context_fb(
    const float* __restrict__ attn, const float* __restrict__ v,
    float* __restrict__ ctx) {
  __shared__ float red[4][DD];
  int row = blockIdx.x;
  int bh = row / UU;
  int b = bh >> 3, h = bh & 7;
  int lane = threadIdx.x & 63;
  int grp = threadIdx.x >> 6;
  const float* a = attn + (long)row * SS;
  float acc = 0.f;
  for (int s = grp; s < SS; s += 4)
    acc += a[s] * v[(((long)b * SS + s) * HH + h) * DD + lane];
  red[grp][lane] = acc;
  __syncthreads();
  if (grp == 0)
    ctx[(long)row * DD + lane] = red[0][lane] + red[1][lane] + red[2][lane] + red[3][lane];
}

extern "C" void kernel_launch(void* const* d_in, const int* in_sizes, int n_in,
                              void* d_out, int out_size, void* d_ws, size_t ws_size,
                              hipStream_t stream) {
  const float* q   = (const float*)d_in[0];
  const float* k   = (const float*)d_in[1];
  const float* v   = (const float*)d_in[2];
  const int*   idx = (const int*)d_in[3];

  float* out  = (float*)d_out;
  float* ctx  = out;                           // B*H*U*D = 46080 floats
  float* attn = out + (long)BB * HH * UU * DD; // B*H*U*S floats

  // Mtop overlays the ctx region (consumed by K3 before K5b writes ctx).
  int* Mtop = (int*)ctx;

  size_t part_bytes = (size_t)2 * 16 * LL * sizeof(float2);   // 1 MB
  if (ws_size >= part_bytes) {
    // split-u K1: partials in ws, combined inside k_topk
    k_compute_M_part<<<BB * HH * LL / 16 * 2, 256, 0, stream>>>(
        q, k, idx, (float2*)d_ws);
    k_topk_t<true><<<BB * HH, 256, 0, stream>>>(
        (const float2*)d_ws, (const float*)nullptr, Mtop);
  } else {
    float* M = attn;                           // overlay (consumed before K3)
    k_compute_M<<<BB * HH * LL / 16, 256, 0, stream>>>(q, k, idx, M);
    k_topk_t<false><<<BB * HH, 256, 0, stream>>>(
        (const float2*)nullptr, M, Mtop);
  }
  k_scores<<<dim3(SS / 256, BB * HH), 256, 0, stream>>>(q, k, Mtop, attn);
  k_softmax<<<BB * HH * UU, 256, 0, stream>>>(attn);

  size_t per_chunk = (size_t)BB * HH * UU * DD * sizeof(float);  // 184320 B
  int nch = 0;
  for (int c = 32; c >= 1; c >>= 1)
    if (ws_size >= per_chunk * (size_t)c) { nch = c; break; }
  if (nch) {
    k_context_part<<<dim3(nch, BB * HH), 256, 0, stream>>>(attn, v, (float*)d_ws, nch);
    k_context_reduce<<<(BB * HH * UU * DD) / 256, 256, 0, stream>>>((const float*)d_ws, ctx, nch);
  } else {
    k_context_fb<<<BB * HH * UU, 256, 0, stream>>>(attn, v, ctx);
  }
}

// Round 7
// 128.655 us; speedup vs baseline: 1.0282x; 1.0282x over previous
//
#include <hip/hip_runtime.h>

#define BB 2
#define LL 4096
#define SS 4096
#define HH 8
#define DD 64
#define UU 45
#define SCALE 0.125f
#define NTILE 16   // s-tiles in scores kernel (4096/256)

// ---------------------------------------------------------------------------
// K1: M[bh*L + l] = max_u(dot) - sum_u(dot)/S over 45 sampled keys.
// Round-5 proven structure: 16-lane slots, per-head float4 gather, width-16
// shuffle reduce, bh in low 4 bits of blockIdx -> XCD pin (per-XCD K working
// set = 2 head-slices = 2MB, L2-resident; FETCH ~19MB).
// ---------------------------------------------------------------------------
__global__ __launch_bounds__(256) void k_compute_M(
    const float* __restrict__ q, const float* __restrict__ k,
    const int* __restrict__ idx, float* __restrict__ M) {
  __shared__ int sidx[16 * UU];
  int tid = threadIdx.x;
  int bh = blockIdx.x & 15;            // low bits -> XCD pin
  int l0 = (blockIdx.x >> 4) << 4;     // 16 l per block
  for (int i = tid; i < 16 * UU; i += 256) sidx[i] = idx[(long)l0 * UU + i];
  __syncthreads();

  int slot = tid >> 4;    // which l within block
  int sub  = tid & 15;    // d-quarter
  int l = l0 + slot;
  int b = bh >> 3, h = bh & 7;

  const float4* qp = (const float4*)(q + (((long)b * LL + l) * HH + h) * DD);
  float4 qq = qp[sub];
  const float* kb = k + (long)b * SS * HH * DD + h * DD;

  float mx = -INFINITY, sm = 0.f;
  #pragma unroll 5
  for (int u = 0; u < UU; ++u) {
    int s = sidx[slot * UU + u];
    float4 kk4 = ((const float4*)(kb + (long)s * (HH * DD)))[sub];
    float p = qq.x * kk4.x + qq.y * kk4.y + qq.z * kk4.z + qq.w * kk4.w;
    #pragma unroll
    for (int off = 8; off; off >>= 1) p += __shfl_xor(p, off, 16);
    mx = fmaxf(mx, p);
    sm += p;
  }
  if (sub == 0) M[(long)bh * LL + l] = mx - sm * (1.0f / SS);
}

// ---------------------------------------------------------------------------
// K2: top-45 per (b,h) via 4-pass radix-select on orderable uint32 keys,
// then rank-based emit. jax.lax.top_k semantics: value desc, ties -> lowest
// index. One block (256 thr) per bh.
// ---------------------------------------------------------------------------
__global__ __launch_bounds__(256) void k_topk(
    const float* __restrict__ M, int* __restrict__ Mtop) {
  __shared__ unsigned keys[LL];        // 16 KB orderable keys
  __shared__ int hist[256];
  __shared__ int wsum[4];
  __shared__ int sh_bin, sh_gtwin;
  __shared__ int ccount, ecount;
  __shared__ unsigned cand_key[64];
  __shared__ int cand_idx[64];
  __shared__ int elist[LL];            // ==T indices (worst-case capacity)

  int bh = blockIdx.x, tid = threadIdx.x;
  int lane = tid & 63, w = tid >> 6;
  const float* m = M + (long)bh * LL;
  for (int i = tid; i < LL; i += 256) {
    union { float f; unsigned u; } cv; cv.f = m[i];
    keys[i] = (cv.u & 0x80000000u) ? ~cv.u : (cv.u | 0x80000000u);
  }
  if (tid == 0) { ccount = 0; ecount = 0; }
  __syncthreads();

  unsigned prefix = 0, pmask = 0;
  int need = UU, above = 0;

  for (int shift = 24; shift >= 0; shift -= 8) {
    hist[tid] = 0;
    __syncthreads();
    #pragma unroll
    for (int j = 0; j < 16; ++j) {
      unsigned kk = keys[tid + (j << 8)];
      if ((kk & pmask) == prefix) atomicAdd(&hist[(kk >> shift) & 255], 1);
    }
    __syncthreads();
    int v = hist[tid];
    int sfx = v;
    #pragma unroll
    for (int st = 1; st < 64; st <<= 1) {
      int o = __shfl_down(sfx, st, 64);
      if (lane + st < 64) sfx += o;
    }
    if (lane == 0) wsum[w] = sfx;
    __syncthreads();
    for (int t = w + 1; t < 4; ++t) sfx += wsum[t];
    int gt = sfx - v;
    if (gt < need && sfx >= need) {
      sh_bin = tid;
      sh_gtwin = gt;
    }
    __syncthreads();
    prefix |= ((unsigned)sh_bin << shift);
    pmask  |= (255u << shift);
    need  -= sh_gtwin;
    above += sh_gtwin;
    __syncthreads();
  }
  unsigned T = prefix;

  #pragma unroll
  for (int j = 0; j < 16; ++j) {
    int i = tid + (j << 8);
    unsigned kk = keys[i];
    if (kk > T)      { int p = atomicAdd(&ccount, 1); cand_key[p] = kk; cand_idx[p] = i; }
    else if (kk == T){ int p = atomicAdd(&ecount, 1); elist[p] = i; }
  }
  __syncthreads();
  int nc = ccount, ne = ecount;
  for (int t = tid; t < nc; t += 256) {
    unsigned kk = cand_key[t]; int ii = cand_idx[t]; int r = 0;
    for (int j = 0; j < nc; ++j)
      r += (cand_key[j] > kk) || (cand_key[j] == kk && cand_idx[j] < ii);
    Mtop[bh * UU + r] = ii;
  }
  for (int t = tid; t < ne; t += 256) {
    int ii = elist[t]; int r = 0;
    for (int j = 0; j < ne; ++j) r += (elist[j] < ii);
    if (r < need) Mtop[bh * UU + above + r] = ii;
  }
}

// ---------------------------------------------------------------------------
// K3': scores + per-tile softmax stats. Writes RAW scaled scores to attn
// and (max, sum_exp) per (u, tile) to ws. Tile stats via LDS transpose +
// wave shuffle reduces; softmax kernel is eliminated (normalization is
// fused into K5's staging pass).
// ---------------------------------------------------------------------------
__global__ __launch_bounds__(256) void k_scores_stats(
    const float* __restrict__ q, const float* __restrict__ k,
    const int* __restrict__ Mtop, float* __restrict__ attn,
    float2* __restrict__ stats) {
  __shared__ float qr[UU * DD];        // 11.5 KB
  __shared__ float sc[UU][260];        // 46.8 KB transposed tile
  int bh = blockIdx.y, tile = blockIdx.x;
  int b = bh >> 3, h = bh & 7;
  int tid = threadIdx.x;
  for (int i = tid; i < UU * DD; i += 256) {
    int u = i >> 6, d = i & 63;
    int l = Mtop[bh * UU + u];
    qr[i] = q[(((long)b * LL + l) * HH + h) * DD + d];
  }
  __syncthreads();
  int s = tile * 256 + tid;
  float4 kr[16];
  const float4* kp = (const float4*)(k + (((long)b * SS + s) * HH + h) * DD);
  #pragma unroll
  for (int j = 0; j < 16; ++j) kr[j] = kp[j];
  for (int u = 0; u < UU; ++u) {
    const float4* qp = (const float4*)(qr + u * DD);
    float acc = 0.f;
    #pragma unroll
    for (int j = 0; j < 16; ++j) {
      float4 qq = qp[j];
      acc += qq.x * kr[j].x + qq.y * kr[j].y + qq.z * kr[j].z + qq.w * kr[j].w;
    }
    acc *= SCALE;
    sc[u][tid] = acc;
    attn[((long)bh * UU + u) * SS + s] = acc;
  }
  __syncthreads();
  int lane = tid & 63, w = tid >> 6;
  for (int u = w; u < UU; u += 4) {
    float a0 = sc[u][lane],       a1 = sc[u][lane + 64];
    float a2 = sc[u][lane + 128], a3 = sc[u][lane + 192];
    float mx = fmaxf(fmaxf(a0, a1), fmaxf(a2, a3));
    #pragma unroll
    for (int off = 32; off; off >>= 1) mx = fmaxf(mx, __shfl_xor(mx, off, 64));
    float e = __expf(a0 - mx) + __expf(a1 - mx) + __expf(a2 - mx) + __expf(a3 - mx);
    #pragma unroll
    for (int off = 32; off; off >>= 1) e += __shfl_xor(e, off, 64);
    if (lane == 0) stats[((long)bh * UU + u) * NTILE + tile] = make_float2(mx, e);
  }
}

// Old plain scores (fallback path when ws is tiny).
__global__ __launch_bounds__(256) void k_scores(
    const float* __restrict__ q, const float* __restrict__ k,
    const int* __restrict__ Mtop, float* __restrict__ attn) {
  __shared__ float qr[UU * DD];
  int bh = blockIdx.y;
  int b = bh >> 3, h = bh & 7;
  for (int i = threadIdx.x; i < UU * DD; i += 256) {
    int u = i >> 6, d = i & 63;
    int l = Mtop[bh * UU + u];
    qr[i] = q[(((long)b * LL + l) * HH + h) * DD + d];
  }
  __syncthreads();
  int s = blockIdx.x * 256 + threadIdx.x;
  float4 kr[16];
  const float4* kp = (const float4*)(k + (((long)b * SS + s) * HH + h) * DD);
  #pragma unroll
  for (int j = 0; j < 16; ++j) kr[j] = kp[j];
  for (int u = 0; u < UU; ++u) {
    const float4* qp = (const float4*)(qr + u * DD);
    float acc = 0.f;
    #pragma unroll
    for (int j = 0; j < 16; ++j) {
      float4 qq = qp[j];
      acc += qq.x * kr[j].x + qq.y * kr[j].y + qq.z * kr[j].z + qq.w * kr[j].w;
    }
    attn[((long)bh * UU + u) * SS + s] = acc * SCALE;
  }
}

// K4 (fallback only): row softmax over S=4096, one block per row, in place.
__global__ __launch_bounds__(256) void k_softmax(float* __restrict__ attn) {
  __shared__ float red[256];
  long row = blockIdx.x;
  float* a = attn + row * SS;
  float v[16];
  float mx = -INFINITY;
  #pragma unroll
  for (int j = 0; j < 16; ++j) {
    v[j] = a[j * 256 + threadIdx.x];
    mx = fmaxf(mx, v[j]);
  }
  red[threadIdx.x] = mx;
  __syncthreads();
  for (int st = 128; st; st >>= 1) {
    if (threadIdx.x < st) red[threadIdx.x] = fmaxf(red[threadIdx.x], red[threadIdx.x + st]);
    __syncthreads();
  }
  mx = red[0];
  __syncthreads();
  float sm = 0.f;
  #pragma unroll
  for (int j = 0; j < 16; ++j) {
    v[j] = __expf(v[j] - mx);
    sm += v[j];
  }
  red[threadIdx.x] = sm;
  __syncthreads();
  for (int st = 128; st; st >>= 1) {
    if (threadIdx.x < st) red[threadIdx.x] += red[threadIdx.x + st];
    __syncthreads();
  }
  float inv = 1.0f / red[0];
  #pragma unroll
  for (int j = 0; j < 16; ++j) a[j * 256 + threadIdx.x] = v[j] * inv;
}

// ---------------------------------------------------------------------------
// K5a: context partials + fused softmax normalization + attn writeback.
// Prologue combines the NTILE tile-stats per u-row (exact two-level softmax
// reduction). Staging pass reads RAW scores, computes p=exp(x-gmax)*inv,
// writes p to LDS (transposed, stride 52) AND to attn (in place, disjoint
// per chunk). All 45 u-accumulators in registers (lane = d).
// ---------------------------------------------------------------------------
__global__ __launch_bounds__(256) void k_context_part(
    float* __restrict__ attn, const float2* __restrict__ stats,
    const float* __restrict__ v, float* __restrict__ part, int nch) {
  __shared__ float smem[4 * UU * DD];   // 11520 floats; staging uses 128*52
  __shared__ float gm[UU], gi[UU];
  int ch = blockIdx.x, bh = blockIdx.y;
  int b = bh >> 3, h = bh & 7;
  int tid = threadIdx.x;
  int ln = tid & 63, w = tid >> 6;
  int chunk = SS / nch;
  int s0 = ch * chunk;
  int nsub = chunk >> 7;                // 128-s sub-tiles

  if (tid < UU) {
    const float2* st = stats + ((long)bh * UU + tid) * NTILE;
    float mx = -INFINITY;
    #pragma unroll
    for (int t = 0; t < NTILE; ++t) mx = fmaxf(mx, st[t].x);
    float sm = 0.f;
    #pragma unroll
    for (int t = 0; t < NTILE; ++t) sm += st[t].y * __expf(st[t].x - mx);
    gm[tid] = mx; gi[tid] = 1.0f / sm;
  }

  float acc[UU];
  #pragma unroll
  for (int u = 0; u < UU; ++u) acc[u] = 0.f;

  const float* vb = v + (long)b * SS * HH * DD + h * DD + ln;

  for (int sub = 0; sub < nsub; ++sub) {
    int sb = s0 + (sub << 7);
    __syncthreads();                    // protects smem reads AND gm/gi init
    for (int i = tid; i < UU * 128; i += 256) {
      int u = i >> 7, si = i & 127;
      long ga = ((long)bh * UU + u) * SS + sb + si;
      float p = __expf(attn[ga] - gm[u]) * gi[u];
      smem[si * 52 + u] = p;
      attn[ga] = p;
    }
    __syncthreads();
    #pragma unroll 2
    for (int j = 0; j < 32; ++j) {
      int sl = (j << 2) + w;
      float vd = vb[(long)(sb + sl) * (HH * DD)];
      const float* ar = smem + sl * 52;
      #pragma unroll
      for (int g = 0; g < 11; ++g) {
        float4 aa = *(const float4*)(ar + g * 4);
        acc[g * 4 + 0] += aa.x * vd;
        acc[g * 4 + 1] += aa.y * vd;
        acc[g * 4 + 2] += aa.z * vd;
        acc[g * 4 + 3] += aa.w * vd;
      }
      acc[44] += ar[44] * vd;
    }
  }

  __syncthreads();
  #pragma unroll
  for (int u = 0; u < UU; ++u) smem[(w * UU + u) * DD + ln] = acc[u];
  __syncthreads();
  long base = ((long)bh * nch + ch) * (UU * DD);
  for (int i = tid; i < UU * DD; i += 256)
    part[base + i] = smem[i] + smem[UU * DD + i] + smem[2 * UU * DD + i] + smem[3 * UU * DD + i];
}

// K5b: sum partials over chunks. 46080 outputs.
__global__ __launch_bounds__(256) void k_context_reduce(
    const float* __restrict__ part, float* __restrict__ ctx, int nch) {
  int g = blockIdx.x * 256 + threadIdx.x;     // < B*H*U*D = 46080
  int bh = g / (UU * DD);
  int r  = g - bh * (UU * DD);
  float s = 0.f;
  for (int ch = 0; ch < nch; ++ch)
    s += part[((long)bh * nch + ch) * (UU * DD) + r];
  ctx[g] = s;
}

// Fallback (row-per-block context) if d_ws is too small.
__global__ __launch_bounds__(256) void k_context_fb(
    const float* __restrict__ attn, const float* __restrict__ v,
    float* __restrict__ ctx) {
  __shared__ float red[4][DD];
  int row = blockIdx.x;
  int bh = row / UU;
  int b = bh >> 3, h = bh & 7;
  int lane = threadIdx.x & 63;
  int grp = threadIdx.x >> 6;
  const float* a = attn + (long)row * SS;
  float acc = 0.f;
  for (int s = grp; s < SS; s += 4)
    acc += a[s] * v[(((long)b * SS + s) * HH + h) * DD + lane];
  red[grp][lane] = acc;
  __syncthreads();
  if (grp == 0)
    ctx[(long)row * DD + lane] = red[0][lane] + red[1][lane] + red[2][lane] + red[3][lane];
}

extern "C" void kernel_launch(void* const* d_in, const int* in_sizes, int n_in,
                              void* d_out, int out_size, void* d_ws, size_t ws_size,
                              hipStream_t stream) {
  const float* q   = (const float*)d_in[0];
  const float* k   = (const float*)d_in[1];
  const float* v   = (const float*)d_in[2];
  const int*   idx = (const int*)d_in[3];

  float* out  = (float*)d_out;
  float* ctx  = out;                           // B*H*U*D = 46080 floats
  float* attn = out + (long)BB * HH * UU * DD; // B*H*U*S floats

  // Scratch overlays on d_out (safe via stream ordering):
  //  - M lives at start of attn region (consumed by K2 before K3 overwrites)
  //  - Mtop lives at start of ctx region (consumed by K3/K5 before K5b writes)
  float* M    = attn;
  int*   Mtop = (int*)ctx;

  k_compute_M<<<BB * HH * LL / 16, 256, 0, stream>>>(q, k, idx, M);
  k_topk<<<BB * HH, 256, 0, stream>>>(M, Mtop);

  // ws layout: [0,128KB) tile stats; [128KB, ...) context partials
  size_t stats_bytes = (size_t)BB * HH * UU * NTILE * sizeof(float2); // 92160
  size_t stats_off   = 131072;
  size_t per_chunk   = (size_t)BB * HH * UU * DD * sizeof(float);     // 184320
  int nch = 0;
  for (int c = 32; c >= 1; c >>= 1)
    if (ws_size >= stats_off + per_chunk * (size_t)c) { nch = c; break; }

  if (nch) {
    float2* stats = (float2*)d_ws;
    float*  part  = (float*)((char*)d_ws + stats_off);
    k_scores_stats<<<dim3(NTILE, BB * HH), 256, 0, stream>>>(q, k, Mtop, attn, stats);
    k_context_part<<<dim3(nch, BB * HH), 256, 0, stream>>>(attn, stats, v, part, nch);
    k_context_reduce<<<(BB * HH * UU * DD) / 256, 256, 0, stream>>>(part, ctx, nch);
  } else {
    k_scores<<<dim3(SS / 256, BB * HH), 256, 0, stream>>>(q, k, Mtop, attn);
    k_softmax<<<BB * HH * UU, 256, 0, stream>>>(attn);
    k_context_fb<<<BB * HH * UU, 256, 0, stream>>>(attn, v, ctx);
  }
  (void)stats_bytes;
}

// Round 8
// 108.651 us; speedup vs baseline: 1.2175x; 1.1841x over previous
//
#include <hip/hip_runtime.h>

#define BB 2
#define LL 4096
#define SS 4096
#define HH 8
#define DD 64
#define UU 45
#define SCALE 0.125f
#define NCH 32     // softmax/context chunks of 128 s
#define CHK 128

// ---------------------------------------------------------------------------
// K1: M[bh*L + l] = max_u(dot) - sum_u(dot)/S over 45 sampled keys.
// Round-5 proven structure: 16-lane slots, per-head float4 gather, width-16
// shuffle reduce, bh in low 4 bits of blockIdx -> XCD pin (per-XCD K working
// set = 2 head-slices = 2MB, L2-resident; FETCH ~19MB).
// ---------------------------------------------------------------------------
__global__ __launch_bounds__(256) void k_compute_M(
    const float* __restrict__ q, const float* __restrict__ k,
    const int* __restrict__ idx, float* __restrict__ M) {
  __shared__ int sidx[16 * UU];
  int tid = threadIdx.x;
  int bh = blockIdx.x & 15;            // low bits -> XCD pin
  int l0 = (blockIdx.x >> 4) << 4;     // 16 l per block
  for (int i = tid; i < 16 * UU; i += 256) sidx[i] = idx[(long)l0 * UU + i];
  __syncthreads();

  int slot = tid >> 4;    // which l within block
  int sub  = tid & 15;    // d-quarter
  int l = l0 + slot;
  int b = bh >> 3, h = bh & 7;

  const float4* qp = (const float4*)(q + (((long)b * LL + l) * HH + h) * DD);
  float4 qq = qp[sub];
  const float* kb = k + (long)b * SS * HH * DD + h * DD;

  float mx = -INFINITY, sm = 0.f;
  #pragma unroll 5
  for (int u = 0; u < UU; ++u) {
    int s = sidx[slot * UU + u];
    float4 kk4 = ((const float4*)(kb + (long)s * (HH * DD)))[sub];
    float p = qq.x * kk4.x + qq.y * kk4.y + qq.z * kk4.z + qq.w * kk4.w;
    #pragma unroll
    for (int off = 8; off; off >>= 1) p += __shfl_xor(p, off, 16);
    mx = fmaxf(mx, p);
    sm += p;
  }
  if (sub == 0) M[(long)bh * LL + l] = mx - sm * (1.0f / SS);
}

// ---------------------------------------------------------------------------
// K2: top-45 per (b,h) via 4-pass radix-select on orderable uint32 keys,
// then rank-based emit. jax.lax.top_k semantics: value desc, ties -> lowest
// index. One block (256 thr) per bh.
// ---------------------------------------------------------------------------
__global__ __launch_bounds__(256) void k_topk(
    const float* __restrict__ M, int* __restrict__ Mtop) {
  __shared__ unsigned keys[LL];
  __shared__ int hist[256];
  __shared__ int wsum[4];
  __shared__ int sh_bin, sh_gtwin;
  __shared__ int ccount, ecount;
  __shared__ unsigned cand_key[64];
  __shared__ int cand_idx[64];
  __shared__ int elist[LL];

  int bh = blockIdx.x, tid = threadIdx.x;
  int lane = tid & 63, w = tid >> 6;
  const float* m = M + (long)bh * LL;
  for (int i = tid; i < LL; i += 256) {
    union { float f; unsigned u; } cv; cv.f = m[i];
    keys[i] = (cv.u & 0x80000000u) ? ~cv.u : (cv.u | 0x80000000u);
  }
  if (tid == 0) { ccount = 0; ecount = 0; }
  __syncthreads();

  unsigned prefix = 0, pmask = 0;
  int need = UU, above = 0;

  for (int shift = 24; shift >= 0; shift -= 8) {
    hist[tid] = 0;
    __syncthreads();
    #pragma unroll
    for (int j = 0; j < 16; ++j) {
      unsigned kk = keys[tid + (j << 8)];
      if ((kk & pmask) == prefix) atomicAdd(&hist[(kk >> shift) & 255], 1);
    }
    __syncthreads();
    int v = hist[tid];
    int sfx = v;
    #pragma unroll
    for (int st = 1; st < 64; st <<= 1) {
      int o = __shfl_down(sfx, st, 64);
      if (lane + st < 64) sfx += o;
    }
    if (lane == 0) wsum[w] = sfx;
    __syncthreads();
    for (int t = w + 1; t < 4; ++t) sfx += wsum[t];
    int gt = sfx - v;
    if (gt < need && sfx >= need) {
      sh_bin = tid;
      sh_gtwin = gt;
    }
    __syncthreads();
    prefix |= ((unsigned)sh_bin << shift);
    pmask  |= (255u << shift);
    need  -= sh_gtwin;
    above += sh_gtwin;
    __syncthreads();
  }
  unsigned T = prefix;

  #pragma unroll
  for (int j = 0; j < 16; ++j) {
    int i = tid + (j << 8);
    unsigned kk = keys[i];
    if (kk > T)      { int p = atomicAdd(&ccount, 1); cand_key[p] = kk; cand_idx[p] = i; }
    else if (kk == T){ int p = atomicAdd(&ecount, 1); elist[p] = i; }
  }
  __syncthreads();
  int nc = ccount, ne = ecount;
  for (int t = tid; t < nc; t += 256) {
    unsigned kk = cand_key[t]; int ii = cand_idx[t]; int r = 0;
    for (int j = 0; j < nc; ++j)
      r += (cand_key[j] > kk) || (cand_key[j] == kk && cand_idx[j] < ii);
    Mtop[bh * UU + r] = ii;
  }
  for (int t = tid; t < ne; t += 256) {
    int ii = elist[t]; int r = 0;
    for (int j = 0; j < ne; ++j) r += (elist[j] < ii);
    if (r < need) Mtop[bh * UU + above + r] = ii;
  }
}

// ---------------------------------------------------------------------------
// KF: fused scores + chunk-softmax + context-partial. grid (NCH, B*H).
// Per block (chunk of 128 s):
//   qr (2880 f) and sp (128x52 f) alias one 11520-float smem region that is
//   later reused for the acc staging.
//   P1: thread=(s,uhalf) computes 45x128 raw scores -> sp[s][u].
//   P2: per-u chunk max (strided+shuffle) -> exp-apply, write p~ to attn
//       (unnormalized) -> per-u chunk sum.  stats (m,l) per (bh,u,ch) -> ws.
//   P3: lane=d context accumulate over 128 s (wave-uniform b128 broadcasts),
//       stage, combine -> unnormalized partials -> ws.
// ---------------------------------------------------------------------------
__global__ __launch_bounds__(256) void k_fused(
    const float* __restrict__ q, const float* __restrict__ k,
    const float* __restrict__ v, const int* __restrict__ Mtop,
    float* __restrict__ attn, float* __restrict__ part,
    float2* __restrict__ stats) {
  __shared__ float smem[4 * UU * DD];   // 11520 floats (45KB)
  __shared__ float gm[UU], gl[UU];
  float* qr = smem;                     // [0, 2880)
  float* sp = smem + UU * DD;           // [2880, 9536): 128*52

  int ch = blockIdx.x, bh = blockIdx.y;
  int b = bh >> 3, h = bh & 7;
  int tid = threadIdx.x;
  int lane = tid & 63, w = tid >> 6;
  int s0 = ch * CHK;

  for (int i = tid; i < UU * DD; i += 256) {
    int u = i >> 6, d = i & 63;
    int l = Mtop[bh * UU + u];
    qr[i] = q[(((long)b * LL + l) * HH + h) * DD + d];
  }
  __syncthreads();

  // P1: scores
  {
    int sl = tid & 127, uh = tid >> 7;
    float4 kr[16];
    const float4* kp = (const float4*)(k + (((long)b * SS + s0 + sl) * HH + h) * DD);
    #pragma unroll
    for (int j = 0; j < 16; ++j) kr[j] = kp[j];
    int u0 = uh ? 23 : 0, u1 = uh ? UU : 23;
    for (int u = u0; u < u1; ++u) {
      const float4* qp = (const float4*)(qr + u * DD);
      float acc = 0.f;
      #pragma unroll
      for (int j = 0; j < 16; ++j) {
        float4 qq = qp[j];
        acc += qq.x * kr[j].x + qq.y * kr[j].y + qq.z * kr[j].z + qq.w * kr[j].w;
      }
      sp[sl * 52 + u] = acc * SCALE;
    }
  }
  __syncthreads();

  // P2a: per-u max over the 128 s
  for (int u = w; u < UU; u += 4) {
    float a0 = sp[lane * 52 + u];
    float a1 = sp[(lane + 64) * 52 + u];
    float mx = fmaxf(a0, a1);
    #pragma unroll
    for (int off = 32; off; off >>= 1) mx = fmaxf(mx, __shfl_xor(mx, off, 64));
    if (lane == 0) gm[u] = mx;
  }
  __syncthreads();
  // P2b: exp apply + unnormalized attn write
  for (int i = tid; i < UU * CHK; i += 256) {
    int u = i >> 7, sl = i & 127;
    float p = __expf(sp[sl * 52 + u] - gm[u]);
    sp[sl * 52 + u] = p;
    attn[((long)bh * UU + u) * SS + s0 + sl] = p;
  }
  __syncthreads();
  // P2c: per-u sum
  for (int u = w; u < UU; u += 4) {
    float a0 = sp[lane * 52 + u];
    float a1 = sp[(lane + 64) * 52 + u];
    float e = a0 + a1;
    #pragma unroll
    for (int off = 32; off; off >>= 1) e += __shfl_xor(e, off, 64);
    if (lane == 0) gl[u] = e;
  }

  // P3: context accumulate (lane = d)
  float acc[UU];
  #pragma unroll
  for (int u = 0; u < UU; ++u) acc[u] = 0.f;
  const float* vb = v + (long)b * SS * HH * DD + h * DD + lane;
  #pragma unroll 2
  for (int j = 0; j < 32; ++j) {
    int sl = (j << 2) + w;
    float vd = vb[(long)(s0 + sl) * (HH * DD)];
    const float* ar = sp + sl * 52;
    #pragma unroll
    for (int g = 0; g < 11; ++g) {
      float4 aa = *(const float4*)(ar + g * 4);
      acc[g * 4 + 0] += aa.x * vd;
      acc[g * 4 + 1] += aa.y * vd;
      acc[g * 4 + 2] += aa.z * vd;
      acc[g * 4 + 3] += aa.w * vd;
    }
    acc[44] += ar[44] * vd;
  }

  __syncthreads();                      // all sp reads done; reuse smem
  #pragma unroll
  for (int u = 0; u < UU; ++u) smem[(w * UU + u) * DD + lane] = acc[u];
  __syncthreads();
  long base = ((long)bh * NCH + ch) * (UU * DD);
  for (int i = tid; i < UU * DD; i += 256)
    part[base + i] = smem[i] + smem[UU * DD + i] + smem[2 * UU * DD + i] + smem[3 * UU * DD + i];
  if (tid < UU)
    stats[((long)bh * UU + tid) * NCH + ch] = make_float2(gm[tid], gl[tid]);
}

// ---------------------------------------------------------------------------
// KE: epilogue. blocks [0,720): rescale one attn row by e^{m_ch-M}/L.
//     blocks [720,900): ctx[e] = sum_ch part*e^{m_ch-M} / L.
// ---------------------------------------------------------------------------
__global__ __launch_bounds__(256) void k_epilogue(
    const float2* __restrict__ stats, const float* __restrict__ part,
    float* __restrict__ attn, float* __restrict__ ctx) {
  __shared__ float f[NCH];
  __shared__ float2 st_s[NCH];
  int bid = blockIdx.x, tid = threadIdx.x;
  if (bid < BB * HH * UU) {
    long row = bid;                     // bh*UU + u
    const float2* st = stats + row * NCH;
    if (tid < NCH) st_s[tid] = st[tid];
    __syncthreads();
    if (tid == 0) {
      float M = -INFINITY;
      #pragma unroll
      for (int c = 0; c < NCH; ++c) M = fmaxf(M, st_s[c].x);
      float L = 0.f;
      #pragma unroll
      for (int c = 0; c < NCH; ++c) L += st_s[c].y * __expf(st_s[c].x - M);
      float inv = 1.0f / L;
      #pragma unroll
      for (int c = 0; c < NCH; ++c) f[c] = __expf(st_s[c].x - M) * inv;
    }
    __syncthreads();
    float4* a = (float4*)(attn + row * SS);
    #pragma unroll
    for (int g = 0; g < 4; ++g) {
      int i4 = g * 256 + tid;           // float4 index, 32 per chunk
      float ff = f[i4 >> 5];
      float4 vv = a[i4];
      vv.x *= ff; vv.y *= ff; vv.z *= ff; vv.w *= ff;
      a[i4] = vv;
    }
  } else {
    int e = (bid - BB * HH * UU) * 256 + tid;   // < 46080
    int bh = e / (UU * DD);
    int r = e - bh * (UU * DD);
    int u = r >> 6;
    const float2* st = stats + ((long)bh * UU + u) * NCH;
    float M = -INFINITY;
    #pragma unroll
    for (int c = 0; c < NCH; ++c) M = fmaxf(M, st[c].x);
    float L = 0.f, s = 0.f;
    #pragma unroll
    for (int c = 0; c < NCH; ++c) {
      float ee = __expf(st[c].x - M);
      L += st[c].y * ee;
      s += part[((long)bh * NCH + c) * (UU * DD) + r] * ee;
    }
    ctx[e] = s / L;
  }
}

// --------------------- fallback path (small ws) ----------------------------
__global__ __launch_bounds__(256) void k_scores(
    const float* __restrict__ q, const float* __restrict__ k,
    const int* __restrict__ Mtop, float* __restrict__ attn) {
  __shared__ float qr[UU * DD];
  int bh = blockIdx.y;
  int b = bh >> 3, h = bh & 7;
  for (int i = threadIdx.x; i < UU * DD; i += 256) {
    int u = i >> 6, d = i & 63;
    int l = Mtop[bh * UU + u];
    qr[i] = q[(((long)b * LL + l) * HH + h) * DD + d];
  }
  __syncthreads();
  int s = blockIdx.x * 256 + threadIdx.x;
  float4 kr[16];
  const float4* kp = (const float4*)(k + (((long)b * SS + s) * HH + h) * DD);
  #pragma unroll
  for (int j = 0; j < 16; ++j) kr[j] = kp[j];
  for (int u = 0; u < UU; ++u) {
    const float4* qp = (const float4*)(qr + u * DD);
    float acc = 0.f;
    #pragma unroll
    for (int j = 0; j < 16; ++j) {
      float4 qq = qp[j];
      acc += qq.x * kr[j].x + qq.y * kr[j].y + qq.z * kr[j].z + qq.w * kr[j].w;
    }
    attn[((long)bh * UU + u) * SS + s] = acc * SCALE;
  }
}

__global__ __launch_bounds__(256) void k_softmax(float* __restrict__ attn) {
  __shared__ float red[256];
  long row = blockIdx.x;
  float* a = attn + row * SS;
  float v[16];
  float mx = -INFINITY;
  #pragma unroll
  for (int j = 0; j < 16; ++j) {
    v[j] = a[j * 256 + threadIdx.x];
    mx = fmaxf(mx, v[j]);
  }
  red[threadIdx.x] = mx;
  __syncthreads();
  for (int st = 128; st; st >>= 1) {
    if (threadIdx.x < st) red[threadIdx.x] = fmaxf(red[threadIdx.x], red[threadIdx.x + st]);
    __syncthreads();
  }
  mx = red[0];
  __syncthreads();
  float sm = 0.f;
  #pragma unroll
  for (int j = 0; j < 16; ++j) {
    v[j] = __expf(v[j] - mx);
    sm += v[j];
  }
  red[threadIdx.x] = sm;
  __syncthreads();
  for (int st = 128; st; st >>= 1) {
    if (threadIdx.x < st) red[threadIdx.x] += red[threadIdx.x + st];
    __syncthreads();
  }
  float inv = 1.0f / red[0];
  #pragma unroll
  for (int j = 0; j < 16; ++j) a[j * 256 + threadIdx.x] = v[j] * inv;
}

__global__ __launch_bounds__(256) void k_context_fb(
    const float* __restrict__ attn, const float* __restrict__ v,
    float* __restrict__ ctx) {
  __shared__ float red[4][DD];
  int row = blockIdx.x;
  int bh = row / UU;
  int b = bh >> 3, h = bh & 7;
  int lane = threadIdx.x & 63;
  int grp = threadIdx.x >> 6;
  const float* a = attn + (long)row * SS;
  float acc = 0.f;
  for (int s = grp; s < SS; s += 4)
    acc += a[s] * v[(((long)b * SS + s) * HH + h) * DD + lane];
  red[grp][lane] = acc;
  __syncthreads();
  if (grp == 0)
    ctx[(long)row * DD + lane] = red[0][lane] + red[1][lane] + red[2][lane] + red[3][lane];
}

extern "C" void kernel_launch(void* const* d_in, const int* in_sizes, int n_in,
                              void* d_out, int out_size, void* d_ws, size_t ws_size,
                              hipStream_t stream) {
  const float* q   = (const float*)d_in[0];
  const float* k   = (const float*)d_in[1];
  const float* v   = (const float*)d_in[2];
  const int*   idx = (const int*)d_in[3];

  float* out  = (float*)d_out;
  float* ctx  = out;                           // B*H*U*D = 46080 floats
  float* attn = out + (long)BB * HH * UU * DD; // B*H*U*S floats

  // Overlays on d_out (stream-ordered write-after-read):
  //  - M at start of attn region (consumed by topk before KF overwrites)
  //  - Mtop at start of ctx region (consumed by KF before KE writes ctx)
  float* M    = attn;
  int*   Mtop = (int*)ctx;

  k_compute_M<<<BB * HH * LL / 16, 256, 0, stream>>>(q, k, idx, M);
  k_topk<<<BB * HH, 256, 0, stream>>>(M, Mtop);

  size_t part_bytes  = (size_t)BB * HH * NCH * UU * DD * sizeof(float);   // 5898240
  size_t stats_bytes = (size_t)BB * HH * UU * NCH * sizeof(float2);       // 184320
  if (ws_size >= part_bytes + stats_bytes) {
    float*  part  = (float*)d_ws;
    float2* stats = (float2*)((char*)d_ws + part_bytes);
    k_fused<<<dim3(NCH, BB * HH), 256, 0, stream>>>(q, k, v, Mtop, attn, part, stats);
    int nctx = (BB * HH * UU * DD) / 256;      // 180
    k_epilogue<<<BB * HH * UU + nctx, 256, 0, stream>>>(stats, part, attn, ctx);
  } else {
    k_scores<<<dim3(SS / 256, BB * HH), 256, 0, stream>>>(q, k, Mtop, attn);
    k_softmax<<<BB * HH * UU, 256, 0, stream>>>(attn);
    k_context_fb<<<BB * HH * UU, 256, 0, stream>>>(attn, v, ctx);
  }
}